// Round 1
// baseline (51.739 us; speedup 1.0000x reference)
//
#include <hip/hip_runtime.h>

#define NB_MAX 64
#define THREADS 256
#define MAX_BLOCKS 2048

__global__ __launch_bounds__(THREADS)
void wbce_partial_kernel(const float* __restrict__ y_pred,
                         const float* __restrict__ y_true,
                         const float* __restrict__ bin_weights,
                         const float* __restrict__ cond,
                         const float* __restrict__ bin_edges,
                         float* __restrict__ partials,
                         long long nq, int qshift, int nb)
{
    __shared__ float s_edges[NB_MAX];
    __shared__ float s_w[NB_MAX];
    int tid = threadIdx.x;
    if (tid < nb) {
        s_edges[tid] = bin_edges[tid];
        s_w[tid] = fmaxf(bin_weights[tid], 0.01f);  // MIN_WEIGHT pre-applied
    }
    __syncthreads();

    const float4* __restrict__ yp4 = (const float4*)y_pred;
    const float4* __restrict__ yt4 = (const float4*)y_true;

    const float EPS = 1e-7f;
    const float PHI = 1.0f - 1e-7f;   // rounds to 0.99999994f, matches f32 clip

    float acc = 0.0f;
    long long stride = (long long)gridDim.x * blockDim.x;
    for (long long q = (long long)blockIdx.x * blockDim.x + tid; q < nq; q += stride) {
        long long row = q >> qshift;          // qpr = D/4 is a power of two (D=16 -> 4)
        float x = cond[row];

        // searchsorted(bin_edges, x, side='left'): first i with edges[i] >= x
        int lo = 0, hi = nb;
        while (lo < hi) {
            int mid = (lo + hi) >> 1;
            if (s_edges[mid] < x) lo = mid + 1; else hi = mid;
        }
        int bin1 = lo < 1 ? 1 : (lo > nb ? nb : lo);   // clip to 1..nb
        float w = s_w[bin1 - 1];

        float4 p4 = yp4[q];
        float4 t4 = yt4[q];
        float s = 0.0f;
        #pragma unroll
        for (int j = 0; j < 4; ++j) {
            float p = ((const float*)&p4)[j];
            float t = ((const float*)&t4)[j];
            p = fminf(fmaxf(p, EPS), PHI);
            // bce = -(t*log(p) + (1-t)*log(1-p)); 1-p exact for p>=0.5 (Sterbenz)
            s += t * __logf(p) + (1.0f - t) * __logf(1.0f - p);
        }
        acc -= w * s;
    }

    // wave (64-lane) shuffle reduce
    #pragma unroll
    for (int off = 32; off > 0; off >>= 1)
        acc += __shfl_down(acc, off, 64);

    __shared__ float s_red[THREADS / 64];
    int wave = tid >> 6;
    int lane = tid & 63;
    if (lane == 0) s_red[wave] = acc;
    __syncthreads();
    if (tid == 0) {
        float b = 0.0f;
        #pragma unroll
        for (int w2 = 0; w2 < THREADS / 64; ++w2) b += s_red[w2];
        partials[blockIdx.x] = b;
    }
}

__global__ __launch_bounds__(THREADS)
void wbce_final_kernel(const float* __restrict__ partials, int n,
                       float* __restrict__ out, float inv_count)
{
    int tid = threadIdx.x;
    float acc = 0.0f;
    for (int i = tid; i < n; i += THREADS) acc += partials[i];

    #pragma unroll
    for (int off = 32; off > 0; off >>= 1)
        acc += __shfl_down(acc, off, 64);

    __shared__ float s_red[THREADS / 64];
    int wave = tid >> 6;
    int lane = tid & 63;
    if (lane == 0) s_red[wave] = acc;
    __syncthreads();
    if (tid == 0) {
        float b = 0.0f;
        #pragma unroll
        for (int w2 = 0; w2 < THREADS / 64; ++w2) b += s_red[w2];
        out[0] = b * inv_count;
    }
}

extern "C" void kernel_launch(void* const* d_in, const int* in_sizes, int n_in,
                              void* d_out, int out_size, void* d_ws, size_t ws_size,
                              hipStream_t stream) {
    const float* y_pred = (const float*)d_in[0];
    const float* y_true = (const float*)d_in[1];
    const float* bw     = (const float*)d_in[2];
    const float* cond   = (const float*)d_in[3];
    const float* edges  = (const float*)d_in[4];

    long long total = in_sizes[0];          // B*D
    long long Bn    = in_sizes[3];          // B
    int D  = (int)(total / Bn);
    int nb = in_sizes[2];

    long long nq  = total / 4;              // float4 quads
    int qpr = D / 4;                        // quads per row (power of two)
    int qshift = 0;
    while ((1 << qshift) < qpr) qshift++;

    float* partials = (float*)d_ws;

    long long want = (nq + THREADS - 1) / THREADS;
    int grid = (int)(want < MAX_BLOCKS ? want : MAX_BLOCKS);
    if (grid < 1) grid = 1;

    wbce_partial_kernel<<<grid, THREADS, 0, stream>>>(
        y_pred, y_true, bw, cond, edges, partials, nq, qshift, nb);

    float inv = 1.0f / (float)total;
    wbce_final_kernel<<<1, THREADS, 0, stream>>>(partials, grid, (float*)d_out, inv);
}

// Round 2
// 48.383 us; speedup vs baseline: 1.0694x; 1.0694x over previous
//
#include <hip/hip_runtime.h>

#define NB_MAX 64
#define THREADS 256
#define MAX_BLOCKS 2048

__global__ __launch_bounds__(THREADS)
void wbce_row_kernel(const float* __restrict__ y_pred,
                     const float* __restrict__ y_true,
                     const float* __restrict__ bin_weights,
                     const float* __restrict__ cond,
                     const float* __restrict__ bin_edges,
                     float* __restrict__ partials,
                     long long nrows, int dqshift, int nb)
{
    __shared__ float s_edges[NB_MAX];
    __shared__ float s_w[NB_MAX];
    int tid = threadIdx.x;
    if (tid < nb) {
        s_edges[tid] = bin_edges[tid];
        s_w[tid] = fmaxf(bin_weights[tid], 0.01f);  // MIN_WEIGHT pre-applied
    }
    __syncthreads();

    const float EPS = 1e-7f;
    const float PHI = 0.99999994f;   // f32(1 - 1e-7)
    const float LN2 = 0.6931471805599453f;
    const int dq = 1 << dqshift;     // float4 quads per row (D/4 = 4)

    float acc = 0.0f;
    long long stride = (long long)gridDim.x * blockDim.x;
    for (long long r = (long long)blockIdx.x * blockDim.x + tid; r < nrows; r += stride) {
        float x = cond[r];           // coalesced: 1 float per lane

        // searchsorted(bin_edges, x, side='left'), once per ROW (was per quad)
        int lo = 0, hi = nb;
        while (lo < hi) {
            int mid = (lo + hi) >> 1;
            if (s_edges[mid] < x) lo = mid + 1; else hi = mid;
        }
        int b1 = lo < 1 ? 1 : (lo > nb ? nb : lo);
        float w = s_w[b1 - 1];

        const float4* __restrict__ yp4 = (const float4*)y_pred + (r << dqshift);
        const float4* __restrict__ yt4 = (const float4*)y_true + (r << dqshift);

        float sA = 0.0f, sB = 0.0f;  // log2-space, dual accumulators
        #pragma unroll 4
        for (int j = 0; j < dq; ++j) {
            float4 p4 = yp4[j];
            float4 t4 = yt4[j];
            #pragma unroll
            for (int k = 0; k < 4; ++k) {
                float p = ((const float*)&p4)[k];
                float t = ((const float*)&t4)[k];
                p = __builtin_amdgcn_fmed3f(p, EPS, PHI);   // clamp, 1 instr
                float lp = __log2f(p);
                float lq = __log2f(1.0f - p);                // exact 1-p for p>=0.5
                sA += lq;
                sB = fmaf(t, lp - lq, sB);
            }
        }
        // bce_row_sum = -(sA + sB) * ln2 ; weighted
        acc = fmaf(-w * LN2, sA + sB, acc);
    }

    // wave (64-lane) shuffle reduce
    #pragma unroll
    for (int off = 32; off > 0; off >>= 1)
        acc += __shfl_down(acc, off, 64);

    __shared__ float s_red[THREADS / 64];
    int wave = tid >> 6;
    int lane = tid & 63;
    if (lane == 0) s_red[wave] = acc;
    __syncthreads();
    if (tid == 0) {
        float b = 0.0f;
        #pragma unroll
        for (int w2 = 0; w2 < THREADS / 64; ++w2) b += s_red[w2];
        partials[blockIdx.x] = b;
    }
}

__global__ __launch_bounds__(THREADS)
void wbce_final_kernel(const float* __restrict__ partials, int n,
                       float* __restrict__ out, float inv_count)
{
    int tid = threadIdx.x;
    float acc = 0.0f;
    for (int i = tid; i < n; i += THREADS) acc += partials[i];

    #pragma unroll
    for (int off = 32; off > 0; off >>= 1)
        acc += __shfl_down(acc, off, 64);

    __shared__ float s_red[THREADS / 64];
    int wave = tid >> 6;
    int lane = tid & 63;
    if (lane == 0) s_red[wave] = acc;
    __syncthreads();
    if (tid == 0) {
        float b = 0.0f;
        #pragma unroll
        for (int w2 = 0; w2 < THREADS / 64; ++w2) b += s_red[w2];
        out[0] = b * inv_count;
    }
}

extern "C" void kernel_launch(void* const* d_in, const int* in_sizes, int n_in,
                              void* d_out, int out_size, void* d_ws, size_t ws_size,
                              hipStream_t stream) {
    const float* y_pred = (const float*)d_in[0];
    const float* y_true = (const float*)d_in[1];
    const float* bw     = (const float*)d_in[2];
    const float* cond   = (const float*)d_in[3];
    const float* edges  = (const float*)d_in[4];

    long long total = in_sizes[0];          // B*D
    long long Bn    = in_sizes[3];          // B
    int D  = (int)(total / Bn);
    int nb = in_sizes[2];

    int dq = D / 4;                         // quads per row (D=16 -> 4, pow2)
    int dqshift = 0;
    while ((1 << dqshift) < dq) dqshift++;

    float* partials = (float*)d_ws;

    long long want = (Bn + THREADS - 1) / THREADS;
    int grid = (int)(want < MAX_BLOCKS ? want : MAX_BLOCKS);
    if (grid < 1) grid = 1;

    wbce_row_kernel<<<grid, THREADS, 0, stream>>>(
        y_pred, y_true, bw, cond, edges, partials, Bn, dqshift, nb);

    float inv = 1.0f / (float)total;
    wbce_final_kernel<<<1, THREADS, 0, stream>>>(partials, grid, (float*)d_out, inv);
}